// Round 3
// baseline (2416.608 us; speedup 1.0000x reference)
//
#include <hip/hip_runtime.h>
#include <hip/hip_bf16.h>
#include <math.h>

typedef unsigned short u16;
typedef unsigned int   u32;

#define NB    4
#define NH    16
#define DHD   64
#define NSEQ  2048
#define DMOD  1024

__device__ __forceinline__ float b2f(u16 b) { return __uint_as_float(((u32)b) << 16); }
__device__ __forceinline__ u16 f2b(float f) {
  u32 x = __float_as_uint(f);
  return (u16)((x + 0x7FFFu + ((x >> 16) & 1u)) >> 16);
}

// ---------------- QKV projection GEMM + head scatter + v-gate ----------------
// qkv[m][e] = sum_k X[m][k] * Win[e][k] + bin[e];  m in [0, B*N), e in [0, 3*D)
// fp32 inputs; q/k/v stored as [B,H,N,DHD] bf16; v rows n < n_ctx gated by sigmoid(ts*trust[n])
__global__ __launch_bounds__(256) void qkv_gemm_kernel(
    const float* __restrict__ X, const float* __restrict__ W, const float* __restrict__ bin,
    const float* __restrict__ trust, const float* __restrict__ ptsc, const int* __restrict__ pnc,
    u16* __restrict__ qW, u16* __restrict__ kW, u16* __restrict__ vW)
{
  __shared__ __align__(16) float As[16][68];
  __shared__ __align__(16) float Bs[16][68];
  const int tid = threadIdx.x;
  const int tx = tid & 15, ty = tid >> 4;
  const int m0 = blockIdx.y << 6;
  const int n0 = blockIdx.x << 6;
  const int lm = tid >> 2;           // 0..63 tile row for staging
  const int lk = (tid & 3) << 2;     // 0,4,8,12 k-offset for staging
  const float* pa = X + (size_t)(m0 + lm) * DMOD + lk;
  const float* pb = W + (size_t)(n0 + lm) * DMOD + lk;
  float c[4][4] = {};
  for (int k0 = 0; k0 < DMOD; k0 += 16) {
    float4 va = *(const float4*)(pa + k0);
    float4 vb = *(const float4*)(pb + k0);
    __syncthreads();
    As[lk+0][lm]=va.x; As[lk+1][lm]=va.y; As[lk+2][lm]=va.z; As[lk+3][lm]=va.w;
    Bs[lk+0][lm]=vb.x; Bs[lk+1][lm]=vb.y; Bs[lk+2][lm]=vb.z; Bs[lk+3][lm]=vb.w;
    __syncthreads();
#pragma unroll
    for (int kk = 0; kk < 16; ++kk) {
      float4 a4 = *(const float4*)&As[kk][ty << 2];
      float4 b4 = *(const float4*)&Bs[kk][tx << 2];
      float a[4] = {a4.x, a4.y, a4.z, a4.w};
      float b[4] = {b4.x, b4.y, b4.z, b4.w};
#pragma unroll
      for (int i = 0; i < 4; ++i)
#pragma unroll
        for (int j = 0; j < 4; ++j) c[i][j] = fmaf(a[i], b[j], c[i][j]);
    }
  }
  const int n_ctx = pnc[0];
  const float ts = ptsc[0];
  const int e0 = n0 + (tx << 2);     // 4 consecutive output cols, same which/head
  const int which = e0 >> 10;
  const int r0 = e0 & 1023;
  const int h = r0 >> 6;
  const int dm = r0 & 63;
  u16* dst = (which == 0) ? qW : ((which == 1) ? kW : vW);
  float bb[4];
#pragma unroll
  for (int j = 0; j < 4; ++j) bb[j] = bin[e0 + j];
#pragma unroll
  for (int i = 0; i < 4; ++i) {
    int m = m0 + (ty << 2) + i;
    int b = m >> 11, n = m & 2047;
    float g = 1.0f;
    if (which == 2 && n < n_ctx)
      g = 1.0f / (1.0f + expf(-ts * trust[n]));
    ushort4 o;
    o.x = f2b((c[i][0] + bb[0]) * g);
    o.y = f2b((c[i][1] + bb[1]) * g);
    o.z = f2b((c[i][2] + bb[2]) * g);
    o.w = f2b((c[i][3] + bb[3]) * g);
    *(ushort4*)(dst + ((size_t)((b * NH + h) * NSEQ + n)) * DHD + dm) = o;
  }
}

// ---------------- Flash attention with column bias ----------------
// One block per (b, h, 64-query tile). Online softmax; PPR log-bias on context cols.
__global__ __launch_bounds__(256) void attn_kernel(
    const u16* __restrict__ qW, const u16* __restrict__ kW, const u16* __restrict__ vW,
    const float* __restrict__ ppr, const float* __restrict__ plpa, const int* __restrict__ pnc,
    u16* __restrict__ aO)
{
  __shared__ __align__(16) float Qt[64][68];    // [d][q]  (transposed)
  __shared__ __align__(16) float KVs[64][68];   // phase 1: K^T [d][k]; phase 2: V [k][d]
  __shared__ __align__(16) float Pt[64][68];    // [k][q]  (transposed P / S)
  __shared__ float m_i[64], l_i[64], alS[64];

  const int tid = threadIdx.x;
  const int tx = tid & 15, ty = tid >> 4;
  const int qt = blockIdx.x & 31;
  const int bh = blockIdx.x >> 5;             // b*NH + h
  const size_t base = (size_t)bh * NSEQ * DHD;
  const int q0 = qt << 6;
  const int n_ctx = pnc[0];
  const float lpa = plpa[0];
  const float scale = 0.125f;                  // 1/sqrt(64)
  const int lrow = tid >> 2;
  const int lseg = (tid & 3) << 4;

  { // stage Q transposed
    const u16* src = qW + base + (size_t)(q0 + lrow) * DHD + lseg;
#pragma unroll
    for (int u = 0; u < 16; u += 4) {
      ushort4 v = *(const ushort4*)(src + u);
      Qt[lseg+u+0][lrow] = b2f(v.x);
      Qt[lseg+u+1][lrow] = b2f(v.y);
      Qt[lseg+u+2][lrow] = b2f(v.z);
      Qt[lseg+u+3][lrow] = b2f(v.w);
    }
  }
  if (tid < 64) { m_i[tid] = -3.0e38f; l_i[tid] = 0.0f; }
  float c[4][4] = {};

  for (int kb = 0; kb < NSEQ; kb += 64) {
    // prefetch K and V rows into registers
    const u16* ksrc = kW + base + (size_t)(kb + lrow) * DHD + lseg;
    const u16* vsrc = vW + base + (size_t)(kb + lrow) * DHD + lseg;
    ushort4 kv[4], vv[4];
#pragma unroll
    for (int u = 0; u < 4; ++u) {
      kv[u] = *(const ushort4*)(ksrc + (u << 2));
      vv[u] = *(const ushort4*)(vsrc + (u << 2));
    }
    __syncthreads();                 // prior iteration done with KVs/Pt
#pragma unroll
    for (int u = 0; u < 4; ++u) {    // K transposed into union buffer
      int d0 = lseg + (u << 2);
      KVs[d0+0][lrow] = b2f(kv[u].x);
      KVs[d0+1][lrow] = b2f(kv[u].y);
      KVs[d0+2][lrow] = b2f(kv[u].z);
      KVs[d0+3][lrow] = b2f(kv[u].w);
    }
    __syncthreads();
    // S tile: s[i][j] = sum_d Q[q0+ty*4+i][d] * K[kb+tx*4+j][d]
    float s[4][4] = {};
#pragma unroll 8
    for (int d = 0; d < 64; ++d) {
      float4 a4 = *(const float4*)&Qt[d][ty << 2];
      float4 b4 = *(const float4*)&KVs[d][tx << 2];
      float a[4] = {a4.x, a4.y, a4.z, a4.w};
      float b[4] = {b4.x, b4.y, b4.z, b4.w};
#pragma unroll
      for (int i = 0; i < 4; ++i)
#pragma unroll
        for (int j = 0; j < 4; ++j) s[i][j] = fmaf(a[i], b[j], s[i][j]);
    }
    // scale + PPR column bias, store transposed P[k][q]
#pragma unroll
    for (int j = 0; j < 4; ++j) {
      int kg = kb + (tx << 2) + j;
      float bias = 0.0f;
      if (kg < n_ctx) bias = -lpa * logf(fmaxf(ppr[kg], 1e-8f));
#pragma unroll
      for (int i = 0; i < 4; ++i)
        Pt[(tx << 2) + j][(ty << 2) + i] = s[i][j] * scale + bias;
    }
    __syncthreads();                 // Kt reads done, Pt written
    // stage V into union buffer (overwrites K^T) while 64 threads do row pass
#pragma unroll
    for (int u = 0; u < 4; ++u) {
      int d0 = lseg + (u << 2);
      float4 vf;
      vf.x = b2f(vv[u].x); vf.y = b2f(vv[u].y); vf.z = b2f(vv[u].z); vf.w = b2f(vv[u].w);
      *(float4*)&KVs[lrow][d0] = vf;
    }
    if (tid < 64) {
      float mo = m_i[tid];
      float mb = -3.0e38f;
      for (int k = 0; k < 64; ++k) mb = fmaxf(mb, Pt[k][tid]);
      float mn = fmaxf(mo, mb);
      float al = expf(mo - mn);
      float sum = 0.0f;
      for (int k = 0; k < 64; ++k) {
        float p = expf(Pt[k][tid] - mn);
        Pt[k][tid] = p;
        sum += p;
      }
      m_i[tid] = mn;
      l_i[tid] = l_i[tid] * al + sum;
      alS[tid] = al;
    }
    __syncthreads();
    // O rescale + P @ V accumulate
    float al[4];
#pragma unroll
    for (int i = 0; i < 4; ++i) al[i] = alS[(ty << 2) + i];
#pragma unroll
    for (int i = 0; i < 4; ++i)
#pragma unroll
      for (int j = 0; j < 4; ++j) c[i][j] *= al[i];
#pragma unroll 8
    for (int k = 0; k < 64; ++k) {
      float4 p4 = *(const float4*)&Pt[k][ty << 2];
      float4 v4 = *(const float4*)&KVs[k][tx << 2];
      float p[4] = {p4.x, p4.y, p4.z, p4.w};
      float v[4] = {v4.x, v4.y, v4.z, v4.w};
#pragma unroll
      for (int i = 0; i < 4; ++i)
#pragma unroll
        for (int j = 0; j < 4; ++j) c[i][j] = fmaf(p[i], v[j], c[i][j]);
    }
  }
  // epilogue: normalize, store to aO [B,N,D] with head interleave
  const int b = bh >> 4, h = bh & 15;
#pragma unroll
  for (int i = 0; i < 4; ++i) {
    int q = q0 + (ty << 2) + i;
    float inv = 1.0f / l_i[(ty << 2) + i];
    ushort4 o;
    o.x = f2b(c[i][0] * inv);
    o.y = f2b(c[i][1] * inv);
    o.z = f2b(c[i][2] * inv);
    o.w = f2b(c[i][3] * inv);
    *(ushort4*)(aO + (size_t)(b * NSEQ + q) * DMOD + h * DHD + (tx << 2)) = o;
  }
}

// ---------------- Output projection GEMM ----------------
// out[m][e] = sum_k aO[m][k] * Wout[e][k] + bout[e];  aO bf16, Wout fp32, out FP32
__global__ __launch_bounds__(256) void oproj_kernel(
    const u16* __restrict__ A, const float* __restrict__ W, const float* __restrict__ bout,
    float* __restrict__ out)
{
  __shared__ __align__(16) float As[16][68];
  __shared__ __align__(16) float Bs[16][68];
  const int tid = threadIdx.x;
  const int tx = tid & 15, ty = tid >> 4;
  const int m0 = blockIdx.y << 6;
  const int n0 = blockIdx.x << 6;
  const int lm = tid >> 2;
  const int lk = (tid & 3) << 2;
  const u16*   pa = A + (size_t)(m0 + lm) * DMOD + lk;
  const float* pb = W + (size_t)(n0 + lm) * DMOD + lk;
  float c[4][4] = {};
  for (int k0 = 0; k0 < DMOD; k0 += 16) {
    ushort4 va = *(const ushort4*)(pa + k0);
    float4  vb = *(const float4*)(pb + k0);
    __syncthreads();
    As[lk+0][lm]=b2f(va.x); As[lk+1][lm]=b2f(va.y); As[lk+2][lm]=b2f(va.z); As[lk+3][lm]=b2f(va.w);
    Bs[lk+0][lm]=vb.x; Bs[lk+1][lm]=vb.y; Bs[lk+2][lm]=vb.z; Bs[lk+3][lm]=vb.w;
    __syncthreads();
#pragma unroll
    for (int kk = 0; kk < 16; ++kk) {
      float4 a4 = *(const float4*)&As[kk][ty << 2];
      float4 b4 = *(const float4*)&Bs[kk][tx << 2];
      float a[4] = {a4.x, a4.y, a4.z, a4.w};
      float b[4] = {b4.x, b4.y, b4.z, b4.w};
#pragma unroll
      for (int i = 0; i < 4; ++i)
#pragma unroll
        for (int j = 0; j < 4; ++j) c[i][j] = fmaf(a[i], b[j], c[i][j]);
    }
  }
  float bb[4];
#pragma unroll
  for (int j = 0; j < 4; ++j) bb[j] = bout[n0 + (tx << 2) + j];
#pragma unroll
  for (int i = 0; i < 4; ++i) {
    int m = m0 + (ty << 2) + i;
    float4 o;
    o.x = c[i][0] + bb[0];
    o.y = c[i][1] + bb[1];
    o.z = c[i][2] + bb[2];
    o.w = c[i][3] + bb[3];
    *(float4*)(out + (size_t)m * DMOD + n0 + (tx << 2)) = o;
  }
}

extern "C" void kernel_launch(void* const* d_in, const int* in_sizes, int n_in,
                              void* d_out, int out_size, void* d_ws, size_t ws_size,
                              hipStream_t stream)
{
  const float* X     = (const float*)d_in[0];
  const int*   pnc   = (const int*)d_in[1];
  const float* ppr   = (const float*)d_in[2];
  const float* trust = (const float*)d_in[3];
  const float* Win   = (const float*)d_in[4];
  const float* bin   = (const float*)d_in[5];
  const float* Wout  = (const float*)d_in[6];
  const float* bout  = (const float*)d_in[7];
  const float* plpa  = (const float*)d_in[8];
  const float* ptsc  = (const float*)d_in[9];
  float* out = (float*)d_out;

  const size_t SZ = (size_t)NB * NH * NSEQ * DHD;   // 8,388,608 elems = 16 MB bf16
  u16* qW = (u16*)d_ws;
  u16* kW = qW + SZ;
  u16* vW = kW + SZ;
  u16* aO = vW + SZ;                                 // [B,N,D] bf16

  // QKV projection: M=8192 rows, 3072 cols
  qkv_gemm_kernel<<<dim3(48, 128), 256, 0, stream>>>(X, Win, bin, trust, ptsc, pnc, qW, kW, vW);
  // attention: B*H=64 head-slices x 32 query tiles
  attn_kernel<<<dim3(2048), 256, 0, stream>>>(qW, kW, vW, ppr, plpa, pnc, aO);
  // output projection: M=8192, 1024 cols
  oproj_kernel<<<dim3(16, 128), 256, 0, stream>>>(aO, Wout, bout, out);
}

// Round 4
// 630.254 us; speedup vs baseline: 3.8343x; 3.8343x over previous
//
#include <hip/hip_runtime.h>
#include <math.h>

typedef unsigned short u16;
typedef unsigned int   u32;
typedef __attribute__((ext_vector_type(8))) short short8;
typedef __attribute__((ext_vector_type(4))) float floatx4;

#define MFMA16(a, b, c) __builtin_amdgcn_mfma_f32_16x16x32_bf16(a, b, c, 0, 0, 0)

__device__ __forceinline__ float b2f(u16 b) { return __uint_as_float(((u32)b) << 16); }
__device__ __forceinline__ u16 f2b(float f) {
  u32 x = __float_as_uint(f);
  return (u16)((x + 0x7FFFu + ((x >> 16) & 1u)) >> 16);
}
__device__ __forceinline__ short8 pack8(float4 a, float4 b) {
  short8 r;
  r[0] = (short)f2b(a.x); r[1] = (short)f2b(a.y); r[2] = (short)f2b(a.z); r[3] = (short)f2b(a.w);
  r[4] = (short)f2b(b.x); r[5] = (short)f2b(b.y); r[6] = (short)f2b(b.z); r[7] = (short)f2b(b.w);
  return r;
}

// ---------------- prep: column bias and value gate ----------------
__global__ void prep_kernel(const float* __restrict__ ppr, const float* __restrict__ trust,
                            const float* __restrict__ plpa, const float* __restrict__ ptsc,
                            const int* __restrict__ pnc,
                            float* __restrict__ colbias, float* __restrict__ vgate)
{
  const int i = blockIdx.x * 256 + threadIdx.x;   // grid 8 -> 2048
  const int n_ctx = pnc[0];
  const float lpa = plpa[0], ts = ptsc[0];
  if (i < 2048) {
    float cb = 0.0f, g = 1.0f;
    if (i < n_ctx) {
      cb = -lpa * logf(fmaxf(ppr[i], 1e-8f));
      g = 1.0f / (1.0f + expf(-ts * trust[i]));
    }
    colbias[i] = cb;
    vgate[i] = g;
  }
}

// ---------------- QKV projection: MFMA GEMM, fp32->bf16 staged ----------------
// C[m][e] = sum_k X[m][k]*Wi[e][k] + bin[e]; q/k -> [bh][n][64]; v -> gated, TRANSPOSED [bh][d][2048]
__global__ __launch_bounds__(256) void qkv_mfma(
    const float* __restrict__ X, const float* __restrict__ Wi, const float* __restrict__ bin,
    const float* __restrict__ vgate,
    u16* __restrict__ qW, u16* __restrict__ kW, u16* __restrict__ vT)
{
  __shared__ __align__(16) u16 SMEM[10240];     // As 128x40 | Bs 128x40 (20480 B)
  u16* As = SMEM;
  u16* Bs = SMEM + 5120;
  const int tid = threadIdx.x;
  const int wave = tid >> 6, lane = tid & 63;
  const int k15 = lane & 15, quad = lane >> 4;
  const int wm = wave & 1, wn = wave >> 1;
  const int m0 = blockIdx.y << 7, n0 = blockIdx.x << 7;
  const int ar = tid >> 2, aseg = tid & 3;      // staging: row, 8-elem segment

  floatx4 c[4][4];
#pragma unroll
  for (int i = 0; i < 4; ++i)
#pragma unroll
    for (int j = 0; j < 4; ++j) c[i][j] = (floatx4){0.f, 0.f, 0.f, 0.f};

  for (int k0 = 0; k0 < 1024; k0 += 32) {
    const float* pA0 = X + (size_t)(m0 + ar) * 1024 + k0 + aseg * 8;
    const float* pA1 = X + (size_t)(m0 + ar + 64) * 1024 + k0 + aseg * 8;
    const float* pB0 = Wi + (size_t)(n0 + ar) * 1024 + k0 + aseg * 8;
    const float* pB1 = Wi + (size_t)(n0 + ar + 64) * 1024 + k0 + aseg * 8;
    float4 a00 = *(const float4*)pA0, a01 = *(const float4*)(pA0 + 4);
    float4 a10 = *(const float4*)pA1, a11 = *(const float4*)(pA1 + 4);
    float4 b00 = *(const float4*)pB0, b01 = *(const float4*)(pB0 + 4);
    float4 b10 = *(const float4*)pB1, b11 = *(const float4*)(pB1 + 4);
    __syncthreads();
    *(short8*)(As + ar * 40 + aseg * 8) = pack8(a00, a01);
    *(short8*)(As + (ar + 64) * 40 + aseg * 8) = pack8(a10, a11);
    *(short8*)(Bs + ar * 40 + aseg * 8) = pack8(b00, b01);
    *(short8*)(Bs + (ar + 64) * 40 + aseg * 8) = pack8(b10, b11);
    __syncthreads();
    short8 af[4], bf[4];
#pragma unroll
    for (int rt = 0; rt < 4; ++rt)
      af[rt] = *(const short8*)(As + (64 * wm + 16 * rt + k15) * 40 + quad * 8);
#pragma unroll
    for (int ct = 0; ct < 4; ++ct)
      bf[ct] = *(const short8*)(Bs + (64 * wn + 16 * ct + k15) * 40 + quad * 8);
#pragma unroll
    for (int rt = 0; rt < 4; ++rt)
#pragma unroll
      for (int ct = 0; ct < 4; ++ct)
        c[rt][ct] = MFMA16(af[rt], bf[ct], c[rt][ct]);
  }

  const int which = n0 >> 10;                   // 0=q 1=k 2=v (block never crosses)
  if (which < 2) {
    u16* dst = which ? kW : qW;
#pragma unroll
    for (int ct = 0; ct < 4; ++ct) {
      const int e = n0 + 64 * wn + 16 * ct + k15;
      const float bb = bin[e];
      const int h = (e >> 6) & 15, d = e & 63;
#pragma unroll
      for (int rt = 0; rt < 4; ++rt)
#pragma unroll
        for (int r = 0; r < 4; ++r) {
          const int m = m0 + 64 * wm + 16 * rt + 4 * quad + r;
          const int b = m >> 11, n = m & 2047;
          dst[(((size_t)(b * 16 + h)) * 2048 + n) * 64 + d] = f2b(c[rt][ct][r] + bb);
        }
    }
  } else {
    // v: gate, then transpose 128x64 half-tiles through LDS -> vT[bh][d][2048]
    const int b = m0 >> 11, nbase = m0 & 2047;
    u16* T = SMEM;                              // 64 x 136 u16 (17408 B)
    for (int half = 0; half < 2; ++half) {
      __syncthreads();
      if (wn == half) {
#pragma unroll
        for (int ct = 0; ct < 4; ++ct) {
          const int el = 16 * ct + k15;         // col within half [0,64)
          const int e = n0 + 64 * half + el;
          const float bb = bin[e];
#pragma unroll
          for (int rt = 0; rt < 4; ++rt)
#pragma unroll
            for (int r = 0; r < 4; ++r) {
              const int ml = 64 * wm + 16 * rt + 4 * quad + r;
              T[el * 136 + ml] = f2b((c[rt][ct][r] + bb) * vgate[nbase + ml]);
            }
        }
      }
      __syncthreads();
#pragma unroll
      for (int uu = 0; uu < 4; ++uu) {
        const int u = tid + uu * 256;
        const int el = u >> 4, moct = u & 15;
        const int e = n0 + 64 * half + el;
        const int h = (e >> 6) & 15, d = e & 63;
        short8 vv = *(const short8*)(T + el * 136 + moct * 8);
        *(short8*)(vT + (((size_t)(b * 16 + h)) * 64 + d) * 2048 + nbase + moct * 8) = vv;
      }
    }
  }
}

// ---------------- Flash attention, MFMA ----------------
// block = (bh, 64-query tile); wave owns 16 queries. K straight [key][d], V pre-transposed [d][key].
__global__ __launch_bounds__(256) void attn_mfma(
    const u16* __restrict__ qW, const u16* __restrict__ kW, const u16* __restrict__ vT,
    const float* __restrict__ colbias, u16* __restrict__ aO)
{
  __shared__ __align__(16) u16 Ks[64 * 72];     // [key][d] pad 72
  __shared__ __align__(16) u16 Vts[64 * 72];    // [d][key] pad 72
  __shared__ __align__(16) u16 Ps[4 * 16 * 72]; // per-wave [q][key] pad 72
  __shared__ float bias_sh[64];

  const int tid = threadIdx.x;
  const int wave = tid >> 6, lane = tid & 63;
  const int k15 = lane & 15, quad = lane >> 4;
  const int qt = blockIdx.x & 31;
  const int bh = blockIdx.x >> 5;
  const size_t base = (size_t)bh * 2048 * 64;   // for qW/kW [bh][n][64]
  const size_t baseV = (size_t)bh * 64 * 2048;  // for vT [bh][d][2048]
  const int q0 = qt << 6;
  const int srow = tid >> 3, sseg = tid & 7;    // staging: row(0..31)+32, 8-elem seg

  // Q a-fragments (A[m=k15][k=quad*8+j(+32)])
  const u16* qp = qW + base + (size_t)(q0 + 16 * wave + k15) * 64 + quad * 8;
  short8 qa0 = *(const short8*)qp;
  short8 qa1 = *(const short8*)(qp + 32);

  floatx4 o[4];
#pragma unroll
  for (int t = 0; t < 4; ++t) o[t] = (floatx4){0.f, 0.f, 0.f, 0.f};
  float m_i[4] = {-3.0e38f, -3.0e38f, -3.0e38f, -3.0e38f};
  float l_i[4] = {0.f, 0.f, 0.f, 0.f};

  for (int kb = 0; kb < 2048; kb += 64) {
    short8 kA = *(const short8*)(kW + base + (size_t)(kb + srow) * 64 + sseg * 8);
    short8 kB = *(const short8*)(kW + base + (size_t)(kb + srow + 32) * 64 + sseg * 8);
    short8 vA = *(const short8*)(vT + baseV + (size_t)srow * 2048 + kb + sseg * 8);
    short8 vB = *(const short8*)(vT + baseV + (size_t)(srow + 32) * 2048 + kb + sseg * 8);
    float bv = 0.f;
    if (tid < 64) bv = colbias[kb + tid];
    __syncthreads();                            // prior iteration reads done
    *(short8*)(Ks + srow * 72 + sseg * 8) = kA;
    *(short8*)(Ks + (srow + 32) * 72 + sseg * 8) = kB;
    *(short8*)(Vts + srow * 72 + sseg * 8) = vA;
    *(short8*)(Vts + (srow + 32) * 72 + sseg * 8) = vB;
    if (tid < 64) bias_sh[tid] = bv;
    __syncthreads();

    // S = Q K^T  (rows 4*quad+r, cols 16t+k15)
    floatx4 s[4];
#pragma unroll
    for (int t = 0; t < 4; ++t) {
      s[t] = (floatx4){0.f, 0.f, 0.f, 0.f};
      const u16* kp = Ks + (16 * t + k15) * 72 + quad * 8;
      short8 kb0 = *(const short8*)kp;
      short8 kb1 = *(const short8*)(kp + 32);
      s[t] = MFMA16(qa0, kb0, s[t]);
      s[t] = MFMA16(qa1, kb1, s[t]);
    }

    float bias_v[4];
#pragma unroll
    for (int t = 0; t < 4; ++t) bias_v[t] = bias_sh[16 * t + k15];

#pragma unroll
    for (int r = 0; r < 4; ++r) {
      float sv[4];
#pragma unroll
      for (int t = 0; t < 4; ++t) sv[t] = s[t][r] * 0.125f + bias_v[t];
      float mx = fmaxf(fmaxf(sv[0], sv[1]), fmaxf(sv[2], sv[3]));
      mx = fmaxf(mx, __shfl_xor(mx, 1));
      mx = fmaxf(mx, __shfl_xor(mx, 2));
      mx = fmaxf(mx, __shfl_xor(mx, 4));
      mx = fmaxf(mx, __shfl_xor(mx, 8));
      const float mn = fmaxf(m_i[r], mx);
      const float al = expf(m_i[r] - mn);
      m_i[r] = mn;
      float sum = 0.f;
      u16 pb[4];
#pragma unroll
      for (int t = 0; t < 4; ++t) {
        float p = expf(sv[t] - mn);
        sum += p;
        pb[t] = f2b(p);
      }
      sum += __shfl_xor(sum, 1);
      sum += __shfl_xor(sum, 2);
      sum += __shfl_xor(sum, 4);
      sum += __shfl_xor(sum, 8);
      l_i[r] = l_i[r] * al + sum;
#pragma unroll
      for (int t = 0; t < 4; ++t) o[t][r] *= al;
#pragma unroll
      for (int t = 0; t < 4; ++t)
        Ps[wave * 1152 + (4 * quad + r) * 72 + 16 * t + k15] = pb[t];
    }
    __syncthreads();                            // P visible (wave-local; safety)

    // O += P V   (A = P[q][key], B = V[key][d] via Vts[d][key])
    const u16* pp = Ps + wave * 1152 + k15 * 72 + quad * 8;
    short8 pa0 = *(const short8*)pp;
    short8 pa1 = *(const short8*)(pp + 32);
#pragma unroll
    for (int t = 0; t < 4; ++t) {
      const u16* vp = Vts + (16 * t + k15) * 72 + quad * 8;
      short8 vb0 = *(const short8*)vp;
      short8 vb1 = *(const short8*)(vp + 32);
      o[t] = MFMA16(pa0, vb0, o[t]);
      o[t] = MFMA16(pa1, vb1, o[t]);
    }
  }

  // epilogue: normalize, store aO [b][n][h*64+d]
  const int b = bh >> 4, h = bh & 15;
#pragma unroll
  for (int r = 0; r < 4; ++r) {
    const int q = q0 + 16 * wave + 4 * quad + r;
    const float inv = 1.0f / l_i[r];
    u16* dst = aO + (size_t)(b * 2048 + q) * 1024 + h * 64;
#pragma unroll
    for (int t = 0; t < 4; ++t)
      dst[16 * t + k15] = f2b(o[t][r] * inv);
  }
}

// ---------------- Output projection: MFMA GEMM, fp32 out ----------------
__global__ __launch_bounds__(256) void oproj_mfma(
    const u16* __restrict__ A, const float* __restrict__ Wo, const float* __restrict__ bout,
    float* __restrict__ out)
{
  __shared__ __align__(16) u16 SMEM[10240];
  u16* As = SMEM;
  u16* Bs = SMEM + 5120;
  const int tid = threadIdx.x;
  const int wave = tid >> 6, lane = tid & 63;
  const int k15 = lane & 15, quad = lane >> 4;
  const int wm = wave & 1, wn = wave >> 1;
  const int m0 = blockIdx.y << 7, n0 = blockIdx.x << 7;
  const int ar = tid >> 2, aseg = tid & 3;

  floatx4 c[4][4];
#pragma unroll
  for (int i = 0; i < 4; ++i)
#pragma unroll
    for (int j = 0; j < 4; ++j) c[i][j] = (floatx4){0.f, 0.f, 0.f, 0.f};

  for (int k0 = 0; k0 < 1024; k0 += 32) {
    short8 a0 = *(const short8*)(A + (size_t)(m0 + ar) * 1024 + k0 + aseg * 8);
    short8 a1 = *(const short8*)(A + (size_t)(m0 + ar + 64) * 1024 + k0 + aseg * 8);
    const float* pB0 = Wo + (size_t)(n0 + ar) * 1024 + k0 + aseg * 8;
    const float* pB1 = Wo + (size_t)(n0 + ar + 64) * 1024 + k0 + aseg * 8;
    float4 b00 = *(const float4*)pB0, b01 = *(const float4*)(pB0 + 4);
    float4 b10 = *(const float4*)pB1, b11 = *(const float4*)(pB1 + 4);
    __syncthreads();
    *(short8*)(As + ar * 40 + aseg * 8) = a0;
    *(short8*)(As + (ar + 64) * 40 + aseg * 8) = a1;
    *(short8*)(Bs + ar * 40 + aseg * 8) = pack8(b00, b01);
    *(short8*)(Bs + (ar + 64) * 40 + aseg * 8) = pack8(b10, b11);
    __syncthreads();
    short8 af[4], bf[4];
#pragma unroll
    for (int rt = 0; rt < 4; ++rt)
      af[rt] = *(const short8*)(As + (64 * wm + 16 * rt + k15) * 40 + quad * 8);
#pragma unroll
    for (int ct = 0; ct < 4; ++ct)
      bf[ct] = *(const short8*)(Bs + (64 * wn + 16 * ct + k15) * 40 + quad * 8);
#pragma unroll
    for (int rt = 0; rt < 4; ++rt)
#pragma unroll
      for (int ct = 0; ct < 4; ++ct)
        c[rt][ct] = MFMA16(af[rt], bf[ct], c[rt][ct]);
  }

#pragma unroll
  for (int ct = 0; ct < 4; ++ct) {
    const int e = n0 + 64 * wn + 16 * ct + k15;
    const float bb = bout[e];
#pragma unroll
    for (int rt = 0; rt < 4; ++rt)
#pragma unroll
      for (int r = 0; r < 4; ++r) {
        const int m = m0 + 64 * wm + 16 * rt + 4 * quad + r;
        out[(size_t)m * 1024 + e] = c[rt][ct][r] + bb;
      }
  }
}

extern "C" void kernel_launch(void* const* d_in, const int* in_sizes, int n_in,
                              void* d_out, int out_size, void* d_ws, size_t ws_size,
                              hipStream_t stream)
{
  const float* X     = (const float*)d_in[0];
  const int*   pnc   = (const int*)d_in[1];
  const float* ppr   = (const float*)d_in[2];
  const float* trust = (const float*)d_in[3];
  const float* Win   = (const float*)d_in[4];
  const float* bin   = (const float*)d_in[5];
  const float* Wout  = (const float*)d_in[6];
  const float* bout  = (const float*)d_in[7];
  const float* plpa  = (const float*)d_in[8];
  const float* ptsc  = (const float*)d_in[9];
  float* out = (float*)d_out;

  const size_t SZ = (size_t)64 * 2048 * 64;     // 8,388,608 elems = 16 MB bf16
  u16* qW = (u16*)d_ws;
  u16* kW = qW + SZ;
  u16* vT = kW + SZ;                            // [bh][d][2048]
  u16* aO = vT + SZ;                            // [B,N,D] bf16
  // scratch parked in d_out; oproj fully overwrites it afterwards
  float* colbias = (float*)d_out;
  float* vgate   = colbias + 2048;

  prep_kernel<<<dim3(8), 256, 0, stream>>>(ppr, trust, plpa, ptsc, pnc, colbias, vgate);
  qkv_mfma<<<dim3(24, 64), 256, 0, stream>>>(X, Win, bin, vgate, qW, kW, vT);
  attn_mfma<<<dim3(2048), 256, 0, stream>>>(qW, kW, vT, colbias, aO);
  oproj_mfma<<<dim3(8, 64), 256, 0, stream>>>(aO, Wout, bout, out);
}

// Round 5
// 427.291 us; speedup vs baseline: 5.6557x; 1.4750x over previous
//
#include <hip/hip_runtime.h>
#include <math.h>

typedef unsigned short u16;
typedef unsigned int   u32;
typedef __attribute__((ext_vector_type(8))) short short8;
typedef __attribute__((ext_vector_type(4))) float floatx4;

#define MFMA16(a, b, c) __builtin_amdgcn_mfma_f32_16x16x32_bf16(a, b, c, 0, 0, 0)

__device__ __forceinline__ float b2f(u16 b) { return __uint_as_float(((u32)b) << 16); }
__device__ __forceinline__ u16 f2b(float f) {
  u32 x = __float_as_uint(f);
  return (u16)((x + 0x7FFFu + ((x >> 16) & 1u)) >> 16);
}
__device__ __forceinline__ short8 pack8(float4 a, float4 b) {
  short8 r;
  r[0] = (short)f2b(a.x); r[1] = (short)f2b(a.y); r[2] = (short)f2b(a.z); r[3] = (short)f2b(a.w);
  r[4] = (short)f2b(b.x); r[5] = (short)f2b(b.y); r[6] = (short)f2b(b.z); r[7] = (short)f2b(b.w);
  return r;
}

// ---------------- prep: column bias and value gate (scratch in d_out) ----------------
__global__ void prep_kernel(const float* __restrict__ ppr, const float* __restrict__ trust,
                            const float* __restrict__ plpa, const float* __restrict__ ptsc,
                            const int* __restrict__ pnc,
                            float* __restrict__ colbias, float* __restrict__ vgate)
{
  const int i = blockIdx.x * 256 + threadIdx.x;   // grid 8 -> 2048
  const int n_ctx = pnc[0];
  const float lpa = plpa[0], ts = ptsc[0];
  if (i < 2048) {
    float cb = 0.0f, g = 1.0f;
    if (i < n_ctx) {
      cb = -lpa * logf(fmaxf(ppr[i], 1e-8f));
      g = 1.0f / (1.0f + expf(-ts * trust[i]));
    }
    colbias[i] = cb;
    vgate[i] = g;
  }
}

// ---------------- fp32 -> bf16 conversion passes ----------------
__global__ __launch_bounds__(256) void convert1(const float* __restrict__ X, const float* __restrict__ Wi,
                                                u16* __restrict__ Xb, u16* __restrict__ Wib)
{
  const size_t i = ((size_t)blockIdx.x * 256 + threadIdx.x) * 8;  // grid 5632 covers 11,534,336
  const float* src;
  u16* dst;
  if (i < 8388608) { src = X + i; dst = Xb + i; }
  else { src = Wi + (i - 8388608); dst = Wib + (i - 8388608); }
  float4 a = *(const float4*)src, b = *(const float4*)(src + 4);
  *(short8*)dst = pack8(a, b);
}

__global__ __launch_bounds__(256) void convert2(const float* __restrict__ Wo, u16* __restrict__ Wob)
{
  const size_t i = ((size_t)blockIdx.x * 256 + threadIdx.x) * 8;  // grid 512 -> 1,048,576
  float4 a = *(const float4*)(Wo + i), b = *(const float4*)(Wo + i + 4);
  *(short8*)(Wob + i) = pack8(a, b);
}

// ---------------- QKV projection: bf16 MFMA GEMM ----------------
// q -> [bh][n][64]; k -> pre-scaled by 0.125, [bh][n][64]; v -> gated, transposed [bh][d][2048]
__global__ __launch_bounds__(256) void qkv_mfma(
    const u16* __restrict__ Xb, const u16* __restrict__ Wib, const float* __restrict__ bin,
    const float* __restrict__ vgate,
    u16* __restrict__ qW, u16* __restrict__ kW, u16* __restrict__ vT)
{
  __shared__ __align__(16) u16 SMEM[10240];     // As 128x40 | Bs 128x40
  u16* As = SMEM;
  u16* Bs = SMEM + 5120;
  const int tid = threadIdx.x;
  const int wave = tid >> 6, lane = tid & 63;
  const int k15 = lane & 15, quad = lane >> 4;
  const int wm = wave & 1, wn = wave >> 1;
  const int m0 = blockIdx.y << 7, n0 = blockIdx.x << 7;
  const int ar = tid >> 1, ah = (tid & 1) << 4; // staging: row 0..127, 16-elem half

  floatx4 c[4][4];
#pragma unroll
  for (int i = 0; i < 4; ++i)
#pragma unroll
    for (int j = 0; j < 4; ++j) c[i][j] = (floatx4){0.f, 0.f, 0.f, 0.f};

  for (int k0 = 0; k0 < 1024; k0 += 32) {
    const u16* pA = Xb + (size_t)(m0 + ar) * 1024 + k0 + ah;
    const u16* pB = Wib + (size_t)(n0 + ar) * 1024 + k0 + ah;
    short8 a0 = *(const short8*)pA, a1 = *(const short8*)(pA + 8);
    short8 b0 = *(const short8*)pB, b1 = *(const short8*)(pB + 8);
    __syncthreads();
    *(short8*)(As + ar * 40 + ah) = a0;
    *(short8*)(As + ar * 40 + ah + 8) = a1;
    *(short8*)(Bs + ar * 40 + ah) = b0;
    *(short8*)(Bs + ar * 40 + ah + 8) = b1;
    __syncthreads();
    short8 af[4], bf[4];
#pragma unroll
    for (int rt = 0; rt < 4; ++rt)
      af[rt] = *(const short8*)(As + (64 * wm + 16 * rt + k15) * 40 + quad * 8);
#pragma unroll
    for (int ct = 0; ct < 4; ++ct)
      bf[ct] = *(const short8*)(Bs + (64 * wn + 16 * ct + k15) * 40 + quad * 8);
#pragma unroll
    for (int rt = 0; rt < 4; ++rt)
#pragma unroll
      for (int ct = 0; ct < 4; ++ct)
        c[rt][ct] = MFMA16(af[rt], bf[ct], c[rt][ct]);
  }

  const int which = n0 >> 10;                   // 0=q 1=k 2=v (block never crosses)
  if (which < 2) {
    u16* dst0 = which ? kW : qW;
    const float ksc = which ? 0.125f : 1.0f;    // fold softmax scale into K
#pragma unroll
    for (int ct = 0; ct < 4; ++ct) {
      const int e = n0 + 64 * wn + 16 * ct + k15;
      const float bb = bin[e];
      const int h = (e >> 6) & 15, d = e & 63;
#pragma unroll
      for (int rt = 0; rt < 4; ++rt)
#pragma unroll
        for (int r = 0; r < 4; ++r) {
          const int m = m0 + 64 * wm + 16 * rt + 4 * quad + r;
          const int b = m >> 11, n = m & 2047;
          dst0[(((size_t)(b * 16 + h)) * 2048 + n) * 64 + d] = f2b((c[rt][ct][r] + bb) * ksc);
        }
    }
  } else {
    // v: gate, transpose 128x64 half-tiles through LDS -> vT[bh][d][2048]
    const int b = m0 >> 11, nbase = m0 & 2047;
    u16* T = SMEM;                              // 64 x 136 u16
    for (int half = 0; half < 2; ++half) {
      __syncthreads();
      if (wn == half) {
#pragma unroll
        for (int ct = 0; ct < 4; ++ct) {
          const int el = 16 * ct + k15;
          const int e = n0 + 64 * half + el;
          const float bb = bin[e];
#pragma unroll
          for (int rt = 0; rt < 4; ++rt)
#pragma unroll
            for (int r = 0; r < 4; ++r) {
              const int ml = 64 * wm + 16 * rt + 4 * quad + r;
              T[el * 136 + ml] = f2b((c[rt][ct][r] + bb) * vgate[nbase + ml]);
            }
        }
      }
      __syncthreads();
#pragma unroll
      for (int uu = 0; uu < 4; ++uu) {
        const int u = tid + uu * 256;
        const int el = u >> 4, moct = u & 15;
        const int e = n0 + 64 * half + el;
        const int h = (e >> 6) & 15, d = e & 63;
        short8 vv = *(const short8*)(T + el * 136 + moct * 8);
        *(short8*)(vT + (((size_t)(b * 16 + h)) * 64 + d) * 2048 + nbase + moct * 8) = vv;
      }
    }
  }
}

// ---------------- Flash attention: S^T = K.Q^T, per-lane softmax ----------------
__global__ __launch_bounds__(256) void attn_mfma(
    const u16* __restrict__ qW, const u16* __restrict__ kW, const u16* __restrict__ vT,
    const float* __restrict__ colbias, u16* __restrict__ aO)
{
  __shared__ __align__(16) u16 Ks[64 * 72];     // [key][d] pad 72
  __shared__ __align__(16) u16 Vts[64 * 72];    // [d][key] pad 72
  __shared__ __align__(16) u16 Ps[4 * 16 * 72]; // per-wave P [q][key] pad 72
  __shared__ float exS[128];                    // per-wave 32: al / l exchange

  const int tid = threadIdx.x;
  const int wave = tid >> 6, lane = tid & 63;
  const int k15 = lane & 15, quad = lane >> 4;
  const int qt = blockIdx.x & 31;
  const int bh = blockIdx.x >> 5;
  const size_t base = (size_t)bh * 2048 * 64;
  const size_t baseV = (size_t)bh * 64 * 2048;
  const int q0 = qt << 6;
  const int srow = tid >> 3, sseg = (tid & 7) << 3;

  // Q fragment, reused as the B operand of K.Q^T every k-block
  const u16* qp = qW + base + (size_t)(q0 + 16 * wave + k15) * 64 + quad * 8;
  short8 qa0 = *(const short8*)qp;
  short8 qa1 = *(const short8*)(qp + 32);

  floatx4 o[4];
#pragma unroll
  for (int t = 0; t < 4; ++t) o[t] = (floatx4){0.f, 0.f, 0.f, 0.f};
  float m_i = -3.0e38f, l_i = 0.f;              // this lane's q = k15

  for (int kb = 0; kb < 2048; kb += 64) {
    short8 kA = *(const short8*)(kW + base + (size_t)(kb + srow) * 64 + sseg);
    short8 kB = *(const short8*)(kW + base + (size_t)(kb + srow + 32) * 64 + sseg);
    short8 vA = *(const short8*)(vT + baseV + (size_t)srow * 2048 + kb + sseg);
    short8 vB = *(const short8*)(vT + baseV + (size_t)(srow + 32) * 2048 + kb + sseg);
    float4 cb[4];
#pragma unroll
    for (int t = 0; t < 4; ++t)
      cb[t] = *(const float4*)(colbias + kb + 16 * t + 4 * quad);
    __syncthreads();                            // prior iteration LDS reads done
    *(short8*)(Ks + srow * 72 + sseg) = kA;
    *(short8*)(Ks + (srow + 32) * 72 + sseg) = kB;
    *(short8*)(Vts + srow * 72 + sseg) = vA;
    *(short8*)(Vts + (srow + 32) * 72 + sseg) = vB;
    __syncthreads();

    // S^T tiles: D[key][q]; acc pre-initialized with the per-key column bias
    floatx4 s[4];
#pragma unroll
    for (int t = 0; t < 4; ++t) {
      s[t] = (floatx4){cb[t].x, cb[t].y, cb[t].z, cb[t].w};
      const u16* kp = Ks + (16 * t + k15) * 72 + quad * 8;
      short8 ka0 = *(const short8*)kp;
      short8 ka1 = *(const short8*)(kp + 32);
      s[t] = MFMA16(ka0, qa0, s[t]);            // K as A, Q as B -> S^T
      s[t] = MFMA16(ka1, qa1, s[t]);
    }

    // per-lane softmax over 16 in-register keys, then cross-quad butterfly
    float mx = s[0][0];
#pragma unroll
    for (int t = 0; t < 4; ++t)
#pragma unroll
      for (int r = 0; r < 4; ++r) mx = fmaxf(mx, s[t][r]);
    mx = fmaxf(mx, __shfl_xor(mx, 16));
    mx = fmaxf(mx, __shfl_xor(mx, 32));
    const float mn = fmaxf(m_i, mx);
    const float al = __expf(m_i - mn);
    m_i = mn;
    float p[4][4];
    float sum = 0.f;
#pragma unroll
    for (int t = 0; t < 4; ++t)
#pragma unroll
      for (int r = 0; r < 4; ++r) {
        p[t][r] = __expf(s[t][r] - mn);
        sum += p[t][r];
      }
    sum += __shfl_xor(sum, 16);
    sum += __shfl_xor(sum, 32);
    l_i = l_i * al + sum;

    // P[q][key]: this lane's 4 keys per tile are contiguous -> b64 writes
#pragma unroll
    for (int t = 0; t < 4; ++t) {
      ushort4 pk;
      pk.x = f2b(p[t][0]); pk.y = f2b(p[t][1]); pk.z = f2b(p[t][2]); pk.w = f2b(p[t][3]);
      *(ushort4*)(Ps + wave * 1152 + k15 * 72 + 16 * t + 4 * quad) = pk;
    }

    // rescale O: need al for q-rows 4*quad+r -> wave-local LDS exchange
    float* aw = exS + wave * 32;
    if (quad == 0) aw[k15] = al;
    float4 al4 = *(const float4*)(aw + 4 * quad);
#pragma unroll
    for (int t = 0; t < 4; ++t)
#pragma unroll
      for (int r = 0; r < 4; ++r) o[t][r] *= al4[r];

    // O += P V   (wave-private P, no barrier needed)
    const u16* pp = Ps + wave * 1152 + k15 * 72 + quad * 8;
    short8 pa0 = *(const short8*)pp;
    short8 pa1 = *(const short8*)(pp + 32);
#pragma unroll
    for (int t = 0; t < 4; ++t) {
      const u16* vp = Vts + (16 * t + k15) * 72 + quad * 8;
      short8 vb0 = *(const short8*)vp;
      short8 vb1 = *(const short8*)(vp + 32);
      o[t] = MFMA16(pa0, vb0, o[t]);
      o[t] = MFMA16(pa1, vb1, o[t]);
    }
  }

  // epilogue: exchange l, normalize, store aO [b][n][h*64+d]
  float* lw = exS + wave * 32 + 16;
  if (quad == 0) lw[k15] = l_i;
  float4 l4 = *(const float4*)(lw + 4 * quad);
  const int b = bh >> 4, h = bh & 15;
#pragma unroll
  for (int r = 0; r < 4; ++r) {
    const int q = q0 + 16 * wave + 4 * quad + r;
    const float inv = 1.0f / l4[r];
    u16* dst = aO + (size_t)(b * 2048 + q) * 1024 + h * 64;
#pragma unroll
    for (int t = 0; t < 4; ++t)
      dst[16 * t + k15] = f2b(o[t][r] * inv);
  }
}

// ---------------- Output projection: bf16 MFMA GEMM, fp32 out ----------------
__global__ __launch_bounds__(256) void oproj_mfma(
    const u16* __restrict__ A, const u16* __restrict__ Wob, const float* __restrict__ bout,
    float* __restrict__ out)
{
  __shared__ __align__(16) u16 SMEM[10240];
  u16* As = SMEM;
  u16* Bs = SMEM + 5120;
  const int tid = threadIdx.x;
  const int wave = tid >> 6, lane = tid & 63;
  const int k15 = lane & 15, quad = lane >> 4;
  const int wm = wave & 1, wn = wave >> 1;
  const int m0 = blockIdx.y << 7, n0 = blockIdx.x << 7;
  const int ar = tid >> 1, ah = (tid & 1) << 4;

  floatx4 c[4][4];
#pragma unroll
  for (int i = 0; i < 4; ++i)
#pragma unroll
    for (int j = 0; j < 4; ++j) c[i][j] = (floatx4){0.f, 0.f, 0.f, 0.f};

  for (int k0 = 0; k0 < 1024; k0 += 32) {
    const u16* pA = A + (size_t)(m0 + ar) * 1024 + k0 + ah;
    const u16* pB = Wob + (size_t)(n0 + ar) * 1024 + k0 + ah;
    short8 a0 = *(const short8*)pA, a1 = *(const short8*)(pA + 8);
    short8 b0 = *(const short8*)pB, b1 = *(const short8*)(pB + 8);
    __syncthreads();
    *(short8*)(As + ar * 40 + ah) = a0;
    *(short8*)(As + ar * 40 + ah + 8) = a1;
    *(short8*)(Bs + ar * 40 + ah) = b0;
    *(short8*)(Bs + ar * 40 + ah + 8) = b1;
    __syncthreads();
    short8 af[4], bf[4];
#pragma unroll
    for (int rt = 0; rt < 4; ++rt)
      af[rt] = *(const short8*)(As + (64 * wm + 16 * rt + k15) * 40 + quad * 8);
#pragma unroll
    for (int ct = 0; ct < 4; ++ct)
      bf[ct] = *(const short8*)(Bs + (64 * wn + 16 * ct + k15) * 40 + quad * 8);
#pragma unroll
    for (int rt = 0; rt < 4; ++rt)
#pragma unroll
      for (int ct = 0; ct < 4; ++ct)
        c[rt][ct] = MFMA16(af[rt], bf[ct], c[rt][ct]);
  }

#pragma unroll
  for (int ct = 0; ct < 4; ++ct) {
    const int e = n0 + 64 * wn + 16 * ct + k15;
    const float bb = bout[e];
#pragma unroll
    for (int rt = 0; rt < 4; ++rt)
#pragma unroll
      for (int r = 0; r < 4; ++r) {
        const int m = m0 + 64 * wm + 16 * rt + 4 * quad + r;
        out[(size_t)m * 1024 + e] = c[rt][ct][r] + bb;
      }
  }
}

extern "C" void kernel_launch(void* const* d_in, const int* in_sizes, int n_in,
                              void* d_out, int out_size, void* d_ws, size_t ws_size,
                              hipStream_t stream)
{
  const float* X     = (const float*)d_in[0];
  const int*   pnc   = (const int*)d_in[1];
  const float* ppr   = (const float*)d_in[2];
  const float* trust = (const float*)d_in[3];
  const float* Win   = (const float*)d_in[4];
  const float* bin   = (const float*)d_in[5];
  const float* Wout  = (const float*)d_in[6];
  const float* bout  = (const float*)d_in[7];
  const float* plpa  = (const float*)d_in[8];
  const float* ptsc  = (const float*)d_in[9];
  float* out = (float*)d_out;

  const size_t SZ = (size_t)64 * 2048 * 64;     // 8,388,608 elems = 16 MB bf16
  u16* Xb = (u16*)d_ws;                         // phase 1-2; aliased by aO in phase 3+
  u16* qW = Xb + SZ;
  u16* kW = qW + SZ;                            // phase 3; aliased by Wob in phase 4+
  u16* vT = kW + SZ;                            // [bh][d][2048]   (total ws = 64 MB)
  u16* aO = Xb;
  u16* Wob = kW;
  // scratch parked in d_out (fully overwritten by oproj at the end):
  float* colbias = (float*)d_out;               // [2048]
  float* vgate   = colbias + 2048;              // [2048]
  u16*   Wib     = (u16*)(vgate + 2048);        // 3072x1024 bf16 = 6 MB

  prep_kernel<<<dim3(8), 256, 0, stream>>>(ppr, trust, plpa, ptsc, pnc, colbias, vgate);
  convert1<<<dim3(5632), 256, 0, stream>>>(X, Win, Xb, Wib);
  qkv_mfma<<<dim3(24, 64), 256, 0, stream>>>(Xb, Wib, bin, vgate, qW, kW, vT);
  attn_mfma<<<dim3(2048), 256, 0, stream>>>(qW, kW, vT, colbias, aO);
  convert2<<<dim3(512), 256, 0, stream>>>(Wout, Wob);
  oproj_mfma<<<dim3(8, 64), 256, 0, stream>>>(aO, Wob, bout, out);
}

// Round 6
// 415.911 us; speedup vs baseline: 5.8104x; 1.0274x over previous
//
#include <hip/hip_runtime.h>
#include <math.h>

typedef unsigned short u16;
typedef unsigned int   u32;
typedef __attribute__((ext_vector_type(8))) short short8;
typedef __attribute__((ext_vector_type(4))) float floatx4;

#define MFMA16(a, b, c) __builtin_amdgcn_mfma_f32_16x16x32_bf16(a, b, c, 0, 0, 0)
#define LOG2E 1.4426950408889634f

__device__ __forceinline__ float b2f(u16 b) { return __uint_as_float(((u32)b) << 16); }
__device__ __forceinline__ u16 f2b(float f) {
  u32 x = __float_as_uint(f);
  return (u16)((x + 0x7FFFu + ((x >> 16) & 1u)) >> 16);
}
__device__ __forceinline__ short8 pack8(float4 a, float4 b) {
  short8 r;
  r[0] = (short)f2b(a.x); r[1] = (short)f2b(a.y); r[2] = (short)f2b(a.z); r[3] = (short)f2b(a.w);
  r[4] = (short)f2b(b.x); r[5] = (short)f2b(b.y); r[6] = (short)f2b(b.z); r[7] = (short)f2b(b.w);
  return r;
}
// async 16B global->LDS (wave-uniform LDS base + lane*16)
__device__ __forceinline__ void gload16(const u16* g, u16* l) {
  __builtin_amdgcn_global_load_lds(
      (const __attribute__((address_space(1))) u32*)g,
      (__attribute__((address_space(3))) u32*)l, 16, 0, 0);
}

// ---------------- prep: column bias (log2-domain) and value gate ----------------
__global__ void prep_kernel(const float* __restrict__ ppr, const float* __restrict__ trust,
                            const float* __restrict__ plpa, const float* __restrict__ ptsc,
                            const int* __restrict__ pnc,
                            float* __restrict__ colbias, float* __restrict__ vgate)
{
  const int i = blockIdx.x * 256 + threadIdx.x;   // grid 8 -> 2048
  const int n_ctx = pnc[0];
  const float lpa = plpa[0], ts = ptsc[0];
  if (i < 2048) {
    float cb = 0.0f, g = 1.0f;
    if (i < n_ctx) {
      cb = -lpa * logf(fmaxf(ppr[i], 1e-8f)) * LOG2E;
      g = 1.0f / (1.0f + expf(-ts * trust[i]));
    }
    colbias[i] = cb;
    vgate[i] = g;
  }
}

// ---------------- fp32 -> bf16 conversion passes ----------------
__global__ __launch_bounds__(256) void convert1(const float* __restrict__ X, const float* __restrict__ Wi,
                                                u16* __restrict__ Xb, u16* __restrict__ Wib)
{
  const size_t i = ((size_t)blockIdx.x * 256 + threadIdx.x) * 8;  // grid 5632 covers 11,534,336
  const float* src;
  u16* dst;
  if (i < 8388608) { src = X + i; dst = Xb + i; }
  else { src = Wi + (i - 8388608); dst = Wib + (i - 8388608); }
  float4 a = *(const float4*)src, b = *(const float4*)(src + 4);
  *(short8*)dst = pack8(a, b);
}

__global__ __launch_bounds__(256) void convert2(const float* __restrict__ Wo, u16* __restrict__ Wob)
{
  const size_t i = ((size_t)blockIdx.x * 256 + threadIdx.x) * 8;  // grid 512 -> 1,048,576
  float4 a = *(const float4*)(Wo + i), b = *(const float4*)(Wo + i + 4);
  *(short8*)(Wob + i) = pack8(a, b);
}

// ---------------- QKV projection: bf16 MFMA GEMM, DMA-staged ----------------
// q -> [bh][n][64]; k -> pre-scaled by 0.125*log2e; v -> gated, transposed [bh][d][2048]
__global__ __launch_bounds__(256) void qkv_mfma(
    const u16* __restrict__ Xb, const u16* __restrict__ Wib, const float* __restrict__ bin,
    const float* __restrict__ vgate,
    u16* __restrict__ qW, u16* __restrict__ kW, u16* __restrict__ vT)
{
  __shared__ __align__(16) u16 SMEM[8704];      // As[128*32] | Bs[128*32]; epilogue T 64x136
  u16* As = SMEM;
  u16* Bs = SMEM + 4096;
  const int tid = threadIdx.x;
  const int wave = tid >> 6, lane = tid & 63;
  const int k15 = lane & 15, quad = lane >> 4;
  const int wm = wave & 1, wn = wave >> 1;
  const int m0 = blockIdx.y << 7, n0 = blockIdx.x << 7;

  // DMA staging addressing: issue j of wave covers tile rows wave*32 + j*16 + lane/4
  const int r0 = (wave << 5) + (lane >> 2);
  const int cc = (lane & 3) << 3;
  const u16* gA = Xb + (size_t)(m0 + r0) * 1024 + cc;
  const u16* gB = Wib + (size_t)(n0 + r0) * 1024 + cc;
  u16* lA = As + (wave << 10);
  u16* lB = Bs + (wave << 10);

  floatx4 c[4][4];
#pragma unroll
  for (int i = 0; i < 4; ++i)
#pragma unroll
    for (int j = 0; j < 4; ++j) c[i][j] = (floatx4){0.f, 0.f, 0.f, 0.f};

  for (int k0 = 0; k0 < 1024; k0 += 32) {
    __syncthreads();                            // prior iteration frag reads done
    gload16(gA + k0, lA);
    gload16(gA + k0 + 16 * 1024, lA + 512);
    gload16(gB + k0, lB);
    gload16(gB + k0 + 16 * 1024, lB + 512);
    __syncthreads();                            // vmcnt drained -> LDS tiles ready
    short8 af[4], bf[4];
#pragma unroll
    for (int rt = 0; rt < 4; ++rt)
      af[rt] = *(const short8*)(As + (64 * wm + 16 * rt + k15) * 32 + quad * 8);
#pragma unroll
    for (int ct = 0; ct < 4; ++ct)
      bf[ct] = *(const short8*)(Bs + (64 * wn + 16 * ct + k15) * 32 + quad * 8);
#pragma unroll
    for (int rt = 0; rt < 4; ++rt)
#pragma unroll
      for (int ct = 0; ct < 4; ++ct)
        c[rt][ct] = MFMA16(af[rt], bf[ct], c[rt][ct]);
  }

  const int which = n0 >> 10;                   // 0=q 1=k 2=v (block never crosses)
  if (which < 2) {
    u16* dst0 = which ? kW : qW;
    const float ksc = which ? 0.125f * LOG2E : 1.0f;   // fold softmax scale + log2e into K
#pragma unroll
    for (int ct = 0; ct < 4; ++ct) {
      const int e = n0 + 64 * wn + 16 * ct + k15;
      const float bb = bin[e];
      const int h = (e >> 6) & 15, d = e & 63;
#pragma unroll
      for (int rt = 0; rt < 4; ++rt)
#pragma unroll
        for (int r = 0; r < 4; ++r) {
          const int m = m0 + 64 * wm + 16 * rt + 4 * quad + r;
          const int b = m >> 11, n = m & 2047;
          dst0[(((size_t)(b * 16 + h)) * 2048 + n) * 64 + d] = f2b((c[rt][ct][r] + bb) * ksc);
        }
    }
  } else {
    // v: gate, transpose 128x64 half-tiles through LDS -> vT[bh][d][2048]
    const int b = m0 >> 11, nbase = m0 & 2047;
    u16* T = SMEM;                              // 64 x 136 u16
    for (int half = 0; half < 2; ++half) {
      __syncthreads();
      if (wn == half) {
#pragma unroll
        for (int ct = 0; ct < 4; ++ct) {
          const int el = 16 * ct + k15;
          const int e = n0 + 64 * half + el;
          const float bb = bin[e];
#pragma unroll
          for (int rt = 0; rt < 4; ++rt)
#pragma unroll
            for (int r = 0; r < 4; ++r) {
              const int ml = 64 * wm + 16 * rt + 4 * quad + r;
              T[el * 136 + ml] = f2b((c[rt][ct][r] + bb) * vgate[nbase + ml]);
            }
        }
      }
      __syncthreads();
#pragma unroll
      for (int uu = 0; uu < 4; ++uu) {
        const int u = tid + uu * 256;
        const int el = u >> 4, moct = u & 15;
        const int e = n0 + 64 * half + el;
        const int h = (e >> 6) & 15, d = e & 63;
        short8 vv = *(const short8*)(T + el * 136 + moct * 8);
        *(short8*)(vT + (((size_t)(b * 16 + h)) * 64 + d) * 2048 + nbase + moct * 8) = vv;
      }
    }
  }
}

// ---------------- Flash attention: S^T = K.Q^T, per-lane softmax (log2 domain) ----------------
__global__ __launch_bounds__(256) void attn_mfma(
    const u16* __restrict__ qW, const u16* __restrict__ kW, const u16* __restrict__ vT,
    const float* __restrict__ colbias, u16* __restrict__ aO)
{
  __shared__ __align__(16) u16 Ks[64 * 72];     // [key][d] pad 72
  __shared__ __align__(16) u16 Vts[64 * 72];    // [d][key] pad 72
  __shared__ __align__(16) u16 Ps[4 * 16 * 72]; // per-wave P [q][key] pad 72
  __shared__ float exS[128];                    // per-wave 32: al / l exchange

  const int tid = threadIdx.x;
  const int wave = tid >> 6, lane = tid & 63;
  const int k15 = lane & 15, quad = lane >> 4;
  const int qt = blockIdx.x & 31;
  const int bh = blockIdx.x >> 5;
  const size_t base = (size_t)bh * 2048 * 64;
  const size_t baseV = (size_t)bh * 64 * 2048;
  const int q0 = qt << 6;
  const int srow = tid >> 3, sseg = (tid & 7) << 3;

  // Q fragment, reused as the B operand of K.Q^T every k-block
  const u16* qp = qW + base + (size_t)(q0 + 16 * wave + k15) * 64 + quad * 8;
  short8 qa0 = *(const short8*)qp;
  short8 qa1 = *(const short8*)(qp + 32);

  floatx4 o[4];
#pragma unroll
  for (int t = 0; t < 4; ++t) o[t] = (floatx4){0.f, 0.f, 0.f, 0.f};
  float m_i = -3.0e38f, l_i = 0.f;              // this lane's q = k15 (log2 domain)

  for (int kb = 0; kb < 2048; kb += 64) {
    short8 kA = *(const short8*)(kW + base + (size_t)(kb + srow) * 64 + sseg);
    short8 kB = *(const short8*)(kW + base + (size_t)(kb + srow + 32) * 64 + sseg);
    short8 vA = *(const short8*)(vT + baseV + (size_t)srow * 2048 + kb + sseg);
    short8 vB = *(const short8*)(vT + baseV + (size_t)(srow + 32) * 2048 + kb + sseg);
    float4 cb[4];
#pragma unroll
    for (int t = 0; t < 4; ++t)
      cb[t] = *(const float4*)(colbias + kb + 16 * t + 4 * quad);
    __syncthreads();                            // prior iteration LDS reads done
    *(short8*)(Ks + srow * 72 + sseg) = kA;
    *(short8*)(Ks + (srow + 32) * 72 + sseg) = kB;
    *(short8*)(Vts + srow * 72 + sseg) = vA;
    *(short8*)(Vts + (srow + 32) * 72 + sseg) = vB;
    __syncthreads();

    // S^T tiles: D[key][q]; acc pre-initialized with the per-key column bias
    floatx4 s[4];
#pragma unroll
    for (int t = 0; t < 4; ++t) {
      s[t] = (floatx4){cb[t].x, cb[t].y, cb[t].z, cb[t].w};
      const u16* kp = Ks + (16 * t + k15) * 72 + quad * 8;
      short8 ka0 = *(const short8*)kp;
      short8 ka1 = *(const short8*)(kp + 32);
      s[t] = MFMA16(ka0, qa0, s[t]);            // K as A, Q as B -> S^T
      s[t] = MFMA16(ka1, qa1, s[t]);
    }

    // per-lane softmax over 16 in-register keys, then cross-quad butterfly
    float mx = s[0][0];
#pragma unroll
    for (int t = 0; t < 4; ++t)
#pragma unroll
      for (int r = 0; r < 4; ++r) mx = fmaxf(mx, s[t][r]);
    mx = fmaxf(mx, __shfl_xor(mx, 16));
    mx = fmaxf(mx, __shfl_xor(mx, 32));
    const float mn = fmaxf(m_i, mx);
    const float al = exp2f(m_i - mn);
    m_i = mn;
    float p[4][4];
    float sum = 0.f;
#pragma unroll
    for (int t = 0; t < 4; ++t)
#pragma unroll
      for (int r = 0; r < 4; ++r) {
        p[t][r] = exp2f(s[t][r] - mn);
        sum += p[t][r];
      }
    sum += __shfl_xor(sum, 16);
    sum += __shfl_xor(sum, 32);
    l_i = l_i * al + sum;

    // P[q][key]: pack 4 contiguous keys via 2x v_perm (trunc-to-bf16), one b64 write
#pragma unroll
    for (int t = 0; t < 4; ++t) {
      u32 lo = __builtin_amdgcn_perm(__float_as_uint(p[t][1]), __float_as_uint(p[t][0]), 0x07060302u);
      u32 hi = __builtin_amdgcn_perm(__float_as_uint(p[t][3]), __float_as_uint(p[t][2]), 0x07060302u);
      *(uint2*)(Ps + wave * 1152 + k15 * 72 + 16 * t + 4 * quad) = (uint2){lo, hi};
    }

    // rescale O: need al for q-rows 4*quad+r -> wave-local LDS exchange
    float* aw = exS + wave * 32;
    if (quad == 0) aw[k15] = al;
    float4 al4 = *(const float4*)(aw + 4 * quad);
#pragma unroll
    for (int t = 0; t < 4; ++t)
#pragma unroll
      for (int r = 0; r < 4; ++r) o[t][r] *= al4[r];

    // O += P V   (wave-private P, no barrier needed)
    const u16* pp = Ps + wave * 1152 + k15 * 72 + quad * 8;
    short8 pa0 = *(const short8*)pp;
    short8 pa1 = *(const short8*)(pp + 32);
#pragma unroll
    for (int t = 0; t < 4; ++t) {
      const u16* vp = Vts + (16 * t + k15) * 72 + quad * 8;
      short8 vb0 = *(const short8*)vp;
      short8 vb1 = *(const short8*)(vp + 32);
      o[t] = MFMA16(pa0, vb0, o[t]);
      o[t] = MFMA16(pa1, vb1, o[t]);
    }
  }

  // epilogue: exchange l, normalize, store aO [b][n][h*64+d]
  float* lw = exS + wave * 32 + 16;
  if (quad == 0) lw[k15] = l_i;
  float4 l4 = *(const float4*)(lw + 4 * quad);
  const int b = bh >> 4, h = bh & 15;
#pragma unroll
  for (int r = 0; r < 4; ++r) {
    const int q = q0 + 16 * wave + 4 * quad + r;
    const float inv = 1.0f / l4[r];
    u16* dst = aO + (size_t)(b * 2048 + q) * 1024 + h * 64;
#pragma unroll
    for (int t = 0; t < 4; ++t)
      dst[16 * t + k15] = f2b(o[t][r] * inv);
  }
}

// ---------------- Output projection: bf16 MFMA GEMM (DMA-staged), fp32 out ----------------
__global__ __launch_bounds__(256) void oproj_mfma(
    const u16* __restrict__ A, const u16* __restrict__ Wob, const float* __restrict__ bout,
    float* __restrict__ out)
{
  __shared__ __align__(16) u16 SMEM[8192];
  u16* As = SMEM;
  u16* Bs = SMEM + 4096;
  const int tid = threadIdx.x;
  const int wave = tid >> 6, lane = tid & 63;
  const int k15 = lane & 15, quad = lane >> 4;
  const int wm = wave & 1, wn = wave >> 1;
  const int m0 = blockIdx.y << 7, n0 = blockIdx.x << 7;

  const int r0 = (wave << 5) + (lane >> 2);
  const int cc = (lane & 3) << 3;
  const u16* gA = A + (size_t)(m0 + r0) * 1024 + cc;
  const u16* gB = Wob + (size_t)(n0 + r0) * 1024 + cc;
  u16* lA = As + (wave << 10);
  u16* lB = Bs + (wave << 10);

  floatx4 c[4][4];
#pragma unroll
  for (int i = 0; i < 4; ++i)
#pragma unroll
    for (int j = 0; j < 4; ++j) c[i][j] = (floatx4){0.f, 0.f, 0.f, 0.f};

  for (int k0 = 0; k0 < 1024; k0 += 32) {
    __syncthreads();
    gload16(gA + k0, lA);
    gload16(gA + k0 + 16 * 1024, lA + 512);
    gload16(gB + k0, lB);
    gload16(gB + k0 + 16 * 1024, lB + 512);
    __syncthreads();
    short8 af[4], bf[4];
#pragma unroll
    for (int rt = 0; rt < 4; ++rt)
      af[rt] = *(const short8*)(As + (64 * wm + 16 * rt + k15) * 32 + quad * 8);
#pragma unroll
    for (int ct = 0; ct < 4; ++ct)
      bf[ct] = *(const short8*)(Bs + (64 * wn + 16 * ct + k15) * 32 + quad * 8);
#pragma unroll
    for (int rt = 0; rt < 4; ++rt)
#pragma unroll
      for (int ct = 0; ct < 4; ++ct)
        c[rt][ct] = MFMA16(af[rt], bf[ct], c[rt][ct]);
  }

#pragma unroll
  for (int ct = 0; ct < 4; ++ct) {
    const int e = n0 + 64 * wn + 16 * ct + k15;
    const float bb = bout[e];
#pragma unroll
    for (int rt = 0; rt < 4; ++rt)
#pragma unroll
      for (int r = 0; r < 4; ++r) {
        const int m = m0 + 64 * wm + 16 * rt + 4 * quad + r;
        out[(size_t)m * 1024 + e] = c[rt][ct][r] + bb;
      }
  }
}

extern "C" void kernel_launch(void* const* d_in, const int* in_sizes, int n_in,
                              void* d_out, int out_size, void* d_ws, size_t ws_size,
                              hipStream_t stream)
{
  const float* X     = (const float*)d_in[0];
  const int*   pnc   = (const int*)d_in[1];
  const float* ppr   = (const float*)d_in[2];
  const float* trust = (const float*)d_in[3];
  const float* Win   = (const float*)d_in[4];
  const float* bin   = (const float*)d_in[5];
  const float* Wout  = (const float*)d_in[6];
  const float* bout  = (const float*)d_in[7];
  const float* plpa  = (const float*)d_in[8];
  const float* ptsc  = (const float*)d_in[9];
  float* out = (float*)d_out;

  const size_t SZ = (size_t)64 * 2048 * 64;     // 8,388,608 elems = 16 MB bf16
  u16* Xb = (u16*)d_ws;                         // phase 1-2; aliased by aO in phase 3+
  u16* qW = Xb + SZ;
  u16* kW = qW + SZ;                            // phase 3; aliased by Wob in phase 4+
  u16* vT = kW + SZ;                            // [bh][d][2048]   (total ws = 64 MB)
  u16* aO = Xb;
  u16* Wob = kW;
  // scratch parked in d_out (fully overwritten by oproj at the end):
  float* colbias = (float*)d_out;               // [2048] (log2-domain)
  float* vgate   = colbias + 2048;              // [2048]
  u16*   Wib     = (u16*)(vgate + 2048);        // 3072x1024 bf16 = 6 MB

  prep_kernel<<<dim3(8), 256, 0, stream>>>(ppr, trust, plpa, ptsc, pnc, colbias, vgate);
  convert1<<<dim3(5632), 256, 0, stream>>>(X, Win, Xb, Wib);
  qkv_mfma<<<dim3(24, 64), 256, 0, stream>>>(Xb, Wib, bin, vgate, qW, kW, vT);
  attn_mfma<<<dim3(2048), 256, 0, stream>>>(qW, kW, vT, colbias, aO);
  convert2<<<dim3(512), 256, 0, stream>>>(Wout, Wob);
  oproj_mfma<<<dim3(8, 64), 256, 0, stream>>>(aO, Wob, bout, out);
}